// Round 9
// baseline (29654.620 us; speedup 1.0000x reference)
//
#include <hip/hip_runtime.h>
#include <stdint.h>

typedef unsigned short ushort_t;
typedef unsigned long long u64;
typedef __attribute__((ext_vector_type(8))) short short8;
typedef __attribute__((ext_vector_type(4))) float f32x4;
typedef __attribute__((ext_vector_type(4))) unsigned int u32x4;

#define WS_W0T_HI 0u
#define WS_W0T_LO (2u<<20)
#define WS_WST_HI (4u<<20)
#define WS_WST_LO (12u<<20)
#define WS_ST     (20u<<20)
#define WS_BAR    (26u<<20)

#define SLOT_ELEMS 262144   // per state slot (hi+lo bf16 planes), elements
#define PLANE 131072        // 256*512
#define SLW 72              // LDS slice row stride in shorts (144B, 16B-aligned)

// state slots (bf16 hi/lo planes): 0=h, 1=s0, 2=s1, 3=s2, 4=s3, 5=s5

__device__ __forceinline__ ushort_t f2bf(float f) {
  unsigned u = __float_as_uint(f);
  u += 0x7FFFu + ((u >> 16) & 1u);          // RNE to bf16
  return (ushort_t)(u >> 16);
}
__device__ __forceinline__ float bf2f(ushort_t h) {
  return __uint_as_float(((unsigned)h) << 16);
}
__device__ __forceinline__ float sigf(float v) { return 1.f / (1.f + __expf(-v)); }

// 16B uncached load (bypass L1/L2, coherent at L3)
__device__ __forceinline__ u32x4 uld16(const void* p) {
  u32x4 r;
  asm volatile("global_load_dwordx4 %0, %1, off sc0 sc1" : "=v"(r) : "v"(p));
  return r;
}

// paired-column state store (uncached 4B words); thread owns one elem
__device__ __forceinline__ void st_state(ushort_t* slot, int eo, float s, int tid) {
  ushort_t hi = f2bf(s);
  ushort_t lo = f2bf(s - bf2f(hi));
  unsigned nh = __shfl_xor((unsigned)hi, 1, 64);
  unsigned nl = __shfl_xor((unsigned)lo, 1, 64);
  if (!(tid & 1)) {
    unsigned wh = (unsigned)hi | (nh << 16);
    unsigned wl = (unsigned)lo | (nl << 16);
    __hip_atomic_store((unsigned*)(slot + eo), wh, __ATOMIC_RELAXED, __HIP_MEMORY_SCOPE_AGENT);
    __hip_atomic_store((unsigned*)(slot + PLANE + eo), wl, __ATOMIC_RELAXED, __HIP_MEMORY_SCOPE_AGENT);
  }
}

// convert 8 f32 (cached loads) -> bf16 hi/lo fragments (stage A x-path)
__device__ __forceinline__ void xcvt(const float* xp, short8& ah, short8& al) {
  f32x4 v0 = *(const f32x4*)xp;
  f32x4 v1 = *(const f32x4*)(xp + 4);
#pragma unroll
  for (int i = 0; i < 4; ++i) {
    ushort_t h0 = f2bf(v0[i]);
    ah[i] = (short)h0; al[i] = (short)f2bf(v0[i] - bf2f(h0));
    ushort_t h1 = f2bf(v1[i]);
    ah[i + 4] = (short)h1; al[i + 4] = (short)f2bf(v1[i] - bf2f(h1));
  }
}

// ---------------- prep: tile-packed transposed hi/lo weights; h0 -> slot0 ---
// Tile layout: per matrix, tile (jb, kbg) holds WT[jb*16+n][kbg*32+kg*8+e]
// at offset (jb*KB+kbg)*512 + (kg*16+n)*8 + e  -> one wave's B-frag = 1KB contig.
extern "C" __global__ void prep_kernel(const float* __restrict__ W0,
                                       const float* __restrict__ Ws,
                                       const float* __restrict__ h0,
                                       char* __restrict__ ws) {
  ushort_t* w0h = (ushort_t*)(ws + WS_W0T_HI);
  ushort_t* w0l = (ushort_t*)(ws + WS_W0T_LO);
  ushort_t* wsh = (ushort_t*)(ws + WS_WST_HI);
  ushort_t* wsl = (ushort_t*)(ws + WS_WST_LO);
  ushort_t* st  = (ushort_t*)(ws + WS_ST);
  const long N0 = 1048576, N1 = 4194304, N2 = 131072;
  long total = N0 + N1 + N2;
  for (long idx = (long)blockIdx.x * blockDim.x + threadIdx.x; idx < total;
       idx += (long)gridDim.x * blockDim.x) {
    if (idx < N0) {                       // W0 (1024x1024), KB=32
      int k = (int)(idx >> 10), j = (int)(idx & 1023);
      float v = W0[k * 1024 + j];
      ushort_t hi = f2bf(v);
      long dst = ((long)(j >> 4) * 32 + (k >> 5)) * 512 +
                 (((k >> 3) & 3) * 16 + (j & 15)) * 8 + (k & 7);
      w0h[dst] = hi;
      w0l[dst] = f2bf(v - bf2f(hi));
    } else if (idx < N0 + N1) {           // Ws[8] (512x1024), KB=16
      long r = idx - N0;
      int i = (int)(r >> 19);
      int r2 = (int)(r & 524287);
      int k = r2 >> 10, j = r2 & 1023;
      float v = Ws[(long)i * 524288 + k * 1024 + j];
      ushort_t hi = f2bf(v);
      long dst = (long)i * 524288 + ((long)(j >> 4) * 16 + (k >> 5)) * 512 +
                 (((k >> 3) & 3) * 16 + (j & 15)) * 8 + (k & 7);
      wsh[dst] = hi;
      wsl[dst] = f2bf(v - bf2f(hi));
    } else {                              // h0 -> slot 0
      int e = (int)(idx - N0 - N1);
      float v = h0[e];
      ushort_t hi = f2bf(v);
      st[0 * SLOT_ELEMS + e] = hi;
      st[0 * SLOT_ELEMS + PLANE + e] = f2bf(v - bf2f(hi));
    }
  }
}

// ---- producer-flag sync ----------------------------------------------------
__device__ __forceinline__ void set_flag(unsigned* flags, int g, int pt, unsigned gen) {
  __syncthreads();   // drains vmcnt per wave: uncached stores at coherence point
  if (threadIdx.x == 0)
    __hip_atomic_store(flags + (g * 16 + pt) * 16, gen, __ATOMIC_RELAXED, __HIP_MEMORY_SCOPE_AGENT);
}
// wave-level poll of this wave's 2 producers (q0, q0+1)
__device__ __forceinline__ void pollw(const unsigned* flags, int g, int q0,
                                      unsigned G, int lane) {
  if (lane < 2) {
    const unsigned* f = flags + (g * 16 + q0 + lane) * 16;
    while (__hip_atomic_load(f, __ATOMIC_RELAXED, __HIP_MEMORY_SCOPE_AGENT) < G)
      __builtin_amdgcn_s_sleep(2);
  }
}

// per-wave slice load: 16 rows x 64 cols hi/lo -> this wave's LDS slice.
// Coalesced: lane (row=lane>>3, part=lane&7) -> 8 lanes cover one 128B row run.
__device__ __forceinline__ void slice_load(const ushort_t* slot, int r0, int k0,
                                           ushort_t* SlH, ushort_t* SlL, int lane) {
  const int row = lane >> 3, part = lane & 7;
  const ushort_t* s = slot + (r0 + row) * 512 + k0 + part * 8;
  u32x4 a0 = uld16(s);
  u32x4 a1 = uld16(s + 8 * 512);
  u32x4 b0 = uld16(s + PLANE);
  u32x4 b1 = uld16(s + PLANE + 8 * 512);
  asm volatile("s_waitcnt vmcnt(0)" ::: "memory");
  __builtin_amdgcn_sched_barrier(0);
  *(u32x4*)(SlH + row * SLW + part * 8) = a0;
  *(u32x4*)(SlH + (row + 8) * SLW + part * 8) = a1;
  *(u32x4*)(SlL + row * SLW + part * 8) = b0;
  *(u32x4*)(SlL + (row + 8) * SLW + part * 8) = b1;
}

__device__ __forceinline__ f32x4 mfma3_4(short8 ah, short8 al, short8 bh, short8 bl, f32x4 acc) {
  acc = __builtin_amdgcn_mfma_f32_16x16x32_bf16(ah, bh, acc, 0, 0, 0);
  acc = __builtin_amdgcn_mfma_f32_16x16x32_bf16(ah, bl, acc, 0, 0, 0);
  acc = __builtin_amdgcn_mfma_f32_16x16x32_bf16(al, bh, acc, 0, 0, 0);
  return acc;
}

// K=64 slice matmul vs NP tiled weight matrices (shared A from this wave's slice)
template<int NP>
__device__ __forceinline__ void mm_slice(const ushort_t* SlH, const ushort_t* SlL,
                                         const ushort_t* const (&wh)[NP],
                                         const ushort_t* const (&wl)[NP],
                                         const int (&jbs)[4], int KB, int kbg0,
                                         int lane, f32x4 (&acc)[NP][4]) {
#pragma unroll
  for (int kb = 0; kb < 2; ++kb) {
    const int ao = (lane & 15) * SLW + kb * 32 + (lane >> 4) * 8;
    short8 ah = *(const short8*)(SlH + ao);
    short8 al = *(const short8*)(SlL + ao);
#pragma unroll
    for (int p = 0; p < NP; ++p)
#pragma unroll
      for (int ct = 0; ct < 4; ++ct) {
        const int tile = (jbs[ct] * KB + kbg0 + kb) * 512 + lane * 8;
        short8 bh = *(const short8*)(wh[p] + tile);
        short8 bl = *(const short8*)(wl[p] + tile);
        acc[p][ct] = mfma3_4(ah, al, bh, bl, acc[p][ct]);
      }
  }
}

// pp[m][w][ct][16][16] f32; C/D layout: col=lane&15, row=(lane>>4)*4+r (verified)
__device__ __forceinline__ void wrpp(float* pp, int m, const f32x4 (&a)[4], int w, int lane) {
  const int col = lane & 15, rb = (lane >> 4) * 4;
#pragma unroll
  for (int ct = 0; ct < 4; ++ct) {
    float* b = pp + (((m * 8 + w) * 4 + ct) * 16) * 16 + col;
#pragma unroll
    for (int r = 0; r < 4; ++r) b[(rb + r) * 16] = a[ct][r];
  }
}
__device__ __forceinline__ void rdpp(const float* pp, int m, int row, int cl,
                                     float& c, float& h) {
  const int ctc = cl >> 4, col = cl & 15;
  float cs = 0.f, hs = 0.f;
#pragma unroll
  for (int w = 0; w < 8; ++w) {
    cs += pp[(((m * 8 + w) * 4 + ctc) * 16 + row) * 16 + col];
    hs += pp[(((m * 8 + w) * 4 + ctc + 2) * 16 + row) * 16 + col];
  }
  c = cs; h = hs;
}

// ---------------- main persistent cooperative kernel -----------------------
extern "C" __global__ void __launch_bounds__(512, 1)
rnn_main(const float* __restrict__ x, float* __restrict__ out, char* __restrict__ ws) {
  __shared__ __align__(16) ushort_t Sl[8][2][16 * SLW];  // 36864B per-wave slices
  __shared__ __align__(16) float pp[2 * 8 * 4 * 16 * 16]; // 65536B partials

  ushort_t* stg = (ushort_t*)(ws + WS_ST);
  unsigned* flags = (unsigned*)(ws + WS_BAR);
  const ushort_t* w0h = (const ushort_t*)(ws + WS_W0T_HI);
  const ushort_t* w0l = (const ushort_t*)(ws + WS_W0T_LO);
  const ushort_t* wsh = (const ushort_t*)(ws + WS_WST_HI);
  const ushort_t* wsl = (const ushort_t*)(ws + WS_WST_LO);

  const int tid = threadIdx.x;
  const int wg = blockIdx.x;
  const int g = wg >> 4, pt = wg & 15;    // XCD = wg%8 = pt%8 -> weight slot pinned
  const int r0 = g * 16;
  const int w = tid >> 6, lane = tid & 63;
  ushort_t* SlH = &Sl[w][0][0];
  ushort_t* SlL = &Sl[w][1][0];
  const int jbs[4] = {2 * pt, 2 * pt + 1, 32 + 2 * pt, 33 + 2 * pt};
  const int q0 = 2 * w;                   // this wave's 2 producers
  const int k0 = w * 64;                  // this wave's K-slice origin

  const int erow = tid >> 5, ecl = tid & 31;    // thread's owned output elem
  const int eo = (r0 + erow) * 512 + pt * 32 + ecl;

  // register-resident gate inputs (sp chain) — init h from slot0 (prep)
  float h_reg = bf2f(stg[eo]) + bf2f(stg[PLANE + eo]);
  float s0_r = 0.f, s1_r = 0.f, s2_r = 0.f, s3_r = 0.f, s5_r = 0.f, sum = 0.f;

  for (int t = 0; t < 400; ++t) {
    const unsigned base = 5u * (unsigned)t;

    // ===== stage A: s0 = h + sig(c)*(tanh(hh) - h), A=[x|h], W0 ============
    {
      f32x4 acc[1][4] = {};
      // x-part first (no flag dependency): overlaps producer finish
      const float* xr = x + (size_t)t * 131072 + (size_t)(r0 + (lane & 15)) * 512
                        + k0 + (lane >> 4) * 8;
#pragma unroll
      for (int kb = 0; kb < 2; ++kb) {
        short8 ah, al; xcvt(xr + kb * 32, ah, al);
#pragma unroll
        for (int ct = 0; ct < 4; ++ct) {
          const int tile = (jbs[ct] * 32 + q0 + kb) * 512 + lane * 8;
          short8 bh = *(const short8*)(w0h + tile);
          short8 bl = *(const short8*)(w0l + tile);
          acc[0][ct] = mfma3_4(ah, al, bh, bl, acc[0][ct]);
        }
      }
      pollw(flags, g, q0, base, lane);    // h producers (E flags of t-1)
      slice_load(stg + 0 * SLOT_ELEMS, r0, k0, SlH, SlL, lane);
      const ushort_t* wh1[1] = {w0h};
      const ushort_t* wl1[1] = {w0l};
      mm_slice<1>(SlH, SlL, wh1, wl1, jbs, 32, 16 + q0, lane, acc);
      wrpp(pp, 0, acc[0], w, lane);
      __syncthreads();
      float c, hh; rdpp(pp, 0, erow, ecl, c, hh);
      s0_r = h_reg + sigf(c) * (tanhf(hh) - h_reg);
      st_state(stg + 1 * SLOT_ELEMS, eo, s0_r, tid);
    }
    set_flag(flags, g, pt, base + 1);

    // ===== stage B: s1 = f(s0, tanh, Ws[0]) ================================
    {
      pollw(flags, g, q0, base + 1, lane);
      slice_load(stg + 1 * SLOT_ELEMS, r0, k0, SlH, SlL, lane);
      f32x4 acc[1][4] = {};
      const ushort_t* wh1[1] = {wsh + 0 * 524288};
      const ushort_t* wl1[1] = {wsl + 0 * 524288};
      mm_slice<1>(SlH, SlL, wh1, wl1, jbs, 16, q0, lane, acc);
      wrpp(pp, 0, acc[0], w, lane);
      __syncthreads();
      float c, hh; rdpp(pp, 0, erow, ecl, c, hh);
      s1_r = s0_r + sigf(c) * (tanhf(hh) - s0_r);
      sum = s1_r;
      st_state(stg + 2 * SLOT_ELEMS, eo, s1_r, tid);
    }
    set_flag(flags, g, pt, base + 2);

    // ===== stage C: s2(relu,Ws1) s3(relu,Ws2) s4(ident,Ws3) from s1 ========
    {
      pollw(flags, g, q0, base + 2, lane);
      slice_load(stg + 2 * SLOT_ELEMS, r0, k0, SlH, SlL, lane);
      f32x4 acc[3][4] = {};
      const ushort_t* wh3[3] = {wsh + 1 * 524288, wsh + 2 * 524288, wsh + 3 * 524288};
      const ushort_t* wl3[3] = {wsl + 1 * 524288, wsl + 2 * 524288, wsl + 3 * 524288};
      mm_slice<3>(SlH, SlL, wh3, wl3, jbs, 16, q0, lane, acc);
      wrpp(pp, 0, acc[0], w, lane);       // s2
      wrpp(pp, 1, acc[1], w, lane);       // s3
      __syncthreads();
      float c, hh;
      rdpp(pp, 0, erow, ecl, c, hh);
      s2_r = s1_r + sigf(c) * (fmaxf(hh, 0.f) - s1_r);
      sum += s2_r;
      st_state(stg + 3 * SLOT_ELEMS, eo, s2_r, tid);
      rdpp(pp, 1, erow, ecl, c, hh);
      s3_r = s1_r + sigf(c) * (fmaxf(hh, 0.f) - s1_r);
      sum += s3_r;
      st_state(stg + 4 * SLOT_ELEMS, eo, s3_r, tid);
      set_flag(flags, g, pt, base + 3);   // D needs only s2/s3 (sync inside)
      wrpp(pp, 0, acc[2], w, lane);       // s4: concat-only
      __syncthreads();
      rdpp(pp, 0, erow, ecl, c, hh);
      sum += s1_r + sigf(c) * (hh - s1_r);
      __syncthreads();                    // protect pp before D's writes
    }

    // ===== stage D: s5 = f(s2,tanh,Ws4); s7 = f(s3,tanh,Ws6) ===============
    {
      pollw(flags, g, q0, base + 3, lane);
      const int row = lane >> 3, part = lane & 7;
      const ushort_t* p2 = stg + 3 * SLOT_ELEMS + (r0 + row) * 512 + k0 + part * 8;
      const ushort_t* p3 = stg + 4 * SLOT_ELEMS + (r0 + row) * 512 + k0 + part * 8;
      u32x4 a0 = uld16(p2), a1 = uld16(p2 + 8 * 512);
      u32x4 a2 = uld16(p2 + PLANE), a3 = uld16(p2 + PLANE + 8 * 512);
      u32x4 c0 = uld16(p3), c1 = uld16(p3 + 8 * 512);
      u32x4 c2 = uld16(p3 + PLANE), c3 = uld16(p3 + PLANE + 8 * 512);
      asm volatile("s_waitcnt vmcnt(4)" ::: "memory");   // s2 chunk ready
      __builtin_amdgcn_sched_barrier(0);
      *(u32x4*)(SlH + row * SLW + part * 8) = a0;
      *(u32x4*)(SlH + (row + 8) * SLW + part * 8) = a1;
      *(u32x4*)(SlL + row * SLW + part * 8) = a2;
      *(u32x4*)(SlL + (row + 8) * SLW + part * 8) = a3;
      f32x4 acc5[1][4] = {}, acc7[1][4] = {};
      const ushort_t* wh4[1] = {wsh + 4 * 524288};
      const ushort_t* wl4[1] = {wsl + 4 * 524288};
      mm_slice<1>(SlH, SlL, wh4, wl4, jbs, 16, q0, lane, acc5);
      asm volatile("s_waitcnt vmcnt(0)" ::: "memory");   // s3 chunk ready
      __builtin_amdgcn_sched_barrier(0);
      *(u32x4*)(SlH + row * SLW + part * 8) = c0;        // wave-local WAR: in-order DS
      *(u32x4*)(SlH + (row + 8) * SLW + part * 8) = c1;
      *(u32x4*)(SlL + row * SLW + part * 8) = c2;
      *(u32x4*)(SlL + (row + 8) * SLW + part * 8) = c3;
      const ushort_t* wh6[1] = {wsh + 6 * 524288};
      const ushort_t* wl6[1] = {wsl + 6 * 524288};
      mm_slice<1>(SlH, SlL, wh6, wl6, jbs, 16, q0, lane, acc7);
      wrpp(pp, 0, acc5[0], w, lane);
      wrpp(pp, 1, acc7[0], w, lane);
      __syncthreads();
      float c, hh;
      rdpp(pp, 0, erow, ecl, c, hh);
      s5_r = s2_r + sigf(c) * (tanhf(hh) - s2_r);
      sum += s5_r;
      st_state(stg + 5 * SLOT_ELEMS, eo, s5_r, tid);
      rdpp(pp, 1, erow, ecl, c, hh);      // s7: concat-only
      sum += s3_r + sigf(c) * (tanhf(hh) - s3_r);
    }
    set_flag(flags, g, pt, base + 4);

    // ===== stage E: s6(sigmoid,Ws5) s8(relu,Ws7) from s5; mean; h ==========
    {
      pollw(flags, g, q0, base + 4, lane);
      slice_load(stg + 5 * SLOT_ELEMS, r0, k0, SlH, SlL, lane);
      f32x4 acc[2][4] = {};
      const ushort_t* wh2[2] = {wsh + 5 * 524288, wsh + 7 * 524288};
      const ushort_t* wl2[2] = {wsl + 5 * 524288, wsl + 7 * 524288};
      mm_slice<2>(SlH, SlL, wh2, wl2, jbs, 16, q0, lane, acc);
      wrpp(pp, 0, acc[0], w, lane);
      wrpp(pp, 1, acc[1], w, lane);
      __syncthreads();
      float c, hh;
      rdpp(pp, 0, erow, ecl, c, hh);
      sum += s5_r + sigf(c) * (sigf(hh) - s5_r);
      rdpp(pp, 1, erow, ecl, c, hh);
      sum += s5_r + sigf(c) * (fmaxf(hh, 0.f) - s5_r);
      h_reg = sum * 0.125f;
      __builtin_nontemporal_store(h_reg, &out[(size_t)t * 131072 + eo]);
      if (t == 399)
        __builtin_nontemporal_store(h_reg, &out[(size_t)400 * 131072 + eo]);
      st_state(stg + 0 * SLOT_ELEMS, eo, h_reg, tid);
    }
    set_flag(flags, g, pt, base + 5);
  }
}

// ---------------- host launch ----------------------------------------------
extern "C" void kernel_launch(void* const* d_in, const int* in_sizes, int n_in,
                              void* d_out, int out_size, void* d_ws, size_t ws_size,
                              hipStream_t stream) {
  const float* x  = (const float*)d_in[0];
  const float* h0 = (const float*)d_in[1];
  const float* W0 = (const float*)d_in[2];
  const float* Ws = (const float*)d_in[3];
  float* out = (float*)d_out;
  char* ws = (char*)d_ws;

  (void)in_sizes; (void)n_in; (void)out_size; (void)ws_size;

  (void)hipMemsetAsync(ws + WS_BAR, 0, 32768, stream);
  hipLaunchKernelGGL(prep_kernel, dim3(2048), dim3(256), 0, stream, W0, Ws, h0, ws);

  void* args[3] = {(void*)&x, (void*)&out, (void*)&ws};
  (void)hipLaunchCooperativeKernel((void*)rnn_main, dim3(256), dim3(512), args, 0, stream);
}

// Round 10
// 20355.437 us; speedup vs baseline: 1.4568x; 1.4568x over previous
//
#include <hip/hip_runtime.h>
#include <stdint.h>

typedef unsigned short ushort_t;
typedef unsigned long long u64;
typedef __attribute__((ext_vector_type(8))) short short8;
typedef __attribute__((ext_vector_type(4))) float f32x4;
typedef __attribute__((ext_vector_type(4))) unsigned int u32x4;
typedef __attribute__((ext_vector_type(16))) float f32x16;

#define WS_W0T_HI 0u
#define WS_W0T_LO (2u<<20)
#define WS_WST_HI (4u<<20)
#define WS_WST_LO (12u<<20)
#define WS_ST     (20u<<20)
#define WS_BAR    (26u<<20)

#define SLOT_ELEMS 262144   // per state slot (hi+lo bf16 planes), elements
#define PLANE 131072        // 256*512

// state slots (bf16 hi/lo planes, FRAGMENT layout): 0=h,1=s0,2=s1,3=s2,4=s3,5=s5
// fragment layout: addr(row,k) = (row>>5)*16384 + (k>>4)*512
//                  + ((row&31) + 32*((k>>3)&1))*8 + (k&7)
// -> one MFMA A-frag tile (32 rows x 16 k) is 1KB contiguous, lane l at l*8.

__device__ __forceinline__ int faddr(int row, int k) {
  return ((row >> 5) << 14) + ((k >> 4) << 9) +
         (((row & 31) + ((k >> 3) & 1) * 32) << 3) + (k & 7);
}

__device__ __forceinline__ ushort_t f2bf(float f) {
  unsigned u = __float_as_uint(f);
  u += 0x7FFFu + ((u >> 16) & 1u);          // RNE to bf16
  return (ushort_t)(u >> 16);
}
__device__ __forceinline__ float bf2f(ushort_t h) {
  return __uint_as_float(((unsigned)h) << 16);
}
__device__ __forceinline__ float sigf(float v) { return 1.f / (1.f + __expf(-v)); }

// 16B uncached load (bypass L1/L2, coherent at L3)
__device__ __forceinline__ u32x4 uld16(const void* p) {
  u32x4 r;
  asm volatile("global_load_dwordx4 %0, %1, off sc0 sc1" : "=v"(r) : "v"(p));
  return r;
}
__device__ __forceinline__ short8 as_s8(u32x4 v) {
  union { u32x4 u; short8 s; } c; c.u = v; return c.s;
}

// paired-column state store (uncached 4B words) at fragment offset fo (even col)
__device__ __forceinline__ void st_state(ushort_t* slot, int fo, float s, int tid) {
  ushort_t hi = f2bf(s);
  ushort_t lo = f2bf(s - bf2f(hi));
  unsigned nh = __shfl_xor((unsigned)hi, 1, 64);
  unsigned nl = __shfl_xor((unsigned)lo, 1, 64);
  if (!(tid & 1)) {
    unsigned wh = (unsigned)hi | (nh << 16);
    unsigned wl = (unsigned)lo | (nl << 16);
    __hip_atomic_store((unsigned*)(slot + fo), wh, __ATOMIC_RELAXED, __HIP_MEMORY_SCOPE_AGENT);
    __hip_atomic_store((unsigned*)(slot + PLANE + fo), wl, __ATOMIC_RELAXED, __HIP_MEMORY_SCOPE_AGENT);
  }
}

// convert 8 f32 (cached loads) -> bf16 hi/lo fragments (stage A x-path)
__device__ __forceinline__ void xcvt(const float* xp, short8& ah, short8& al) {
  f32x4 v0 = *(const f32x4*)xp;
  f32x4 v1 = *(const f32x4*)(xp + 4);
#pragma unroll
  for (int i = 0; i < 4; ++i) {
    ushort_t h0 = f2bf(v0[i]);
    ah[i] = (short)h0; al[i] = (short)f2bf(v0[i] - bf2f(h0));
    ushort_t h1 = f2bf(v1[i]);
    ah[i + 4] = (short)h1; al[i + 4] = (short)f2bf(v1[i] - bf2f(h1));
  }
}

// ---------------- prep: round-6 weight layout; h0 -> fragment slot0 ---------
extern "C" __global__ void prep_kernel(const float* __restrict__ W0,
                                       const float* __restrict__ Ws,
                                       const float* __restrict__ h0,
                                       char* __restrict__ ws) {
  ushort_t* w0h = (ushort_t*)(ws + WS_W0T_HI);
  ushort_t* w0l = (ushort_t*)(ws + WS_W0T_LO);
  ushort_t* wsh = (ushort_t*)(ws + WS_WST_HI);
  ushort_t* wsl = (ushort_t*)(ws + WS_WST_LO);
  ushort_t* st  = (ushort_t*)(ws + WS_ST);
  const long N0 = 1048576, N1 = 4194304, N2 = 131072;
  long total = N0 + N1 + N2;
  for (long idx = (long)blockIdx.x * blockDim.x + threadIdx.x; idx < total;
       idx += (long)gridDim.x * blockDim.x) {
    if (idx < N0) {                       // W0T[j][k] from W0[k][j], K=1024
      int k = (int)(idx >> 10), j = (int)(idx & 1023);
      float v = W0[k * 1024 + j];
      ushort_t hi = f2bf(v);
      w0h[j * 1024 + k] = hi;
      w0l[j * 1024 + k] = f2bf(v - bf2f(hi));
    } else if (idx < N0 + N1) {           // WsT[i][j][k] from Ws[i][k][j], K=512
      long r = idx - N0;
      int i = (int)(r >> 19);
      int r2 = (int)(r & 524287);
      int k = r2 >> 10, j = r2 & 1023;
      float v = Ws[(long)i * 524288 + k * 1024 + j];
      ushort_t hi = f2bf(v);
      wsh[(long)i * 524288 + j * 512 + k] = hi;
      wsl[(long)i * 524288 + j * 512 + k] = f2bf(v - bf2f(hi));
    } else {                              // h0 -> slot 0 (fragment layout)
      int e = (int)(idx - N0 - N1);
      int row = e >> 9, col = e & 511;
      float v = h0[e];
      ushort_t hi = f2bf(v);
      int fa = faddr(row, col);
      st[fa] = hi;
      st[PLANE + fa] = f2bf(v - bf2f(hi));
    }
  }
}

// ---- producer-flag sync ----------------------------------------------------
__device__ __forceinline__ void set_flag(unsigned* flags, int g, int pt, unsigned gen) {
  __syncthreads();   // drains vmcnt per wave: uncached stores at coherence point
  if (threadIdx.x == 0)
    __hip_atomic_store(flags + (g * 32 + pt) * 16, gen, __ATOMIC_RELAXED, __HIP_MEMORY_SCOPE_AGENT);
}
// wave-scope poll of this wave's 4 producers {4w..4w+3} (K-slice owners)
__device__ __forceinline__ void pollw(const unsigned* flags, int g, int q0,
                                      unsigned G, int lane) {
  if (lane < 4) {
    const unsigned* f = flags + (g * 32 + q0 + lane) * 16;
    while (__hip_atomic_load(f, __ATOMIC_RELAXED, __HIP_MEMORY_SCOPE_AGENT) < G)
      __builtin_amdgcn_s_sleep(2);
  }
}

// wave's 4 A-frag tiles (K=64 slice) of a slot, straight to registers.
// Each uld16 is 64 lanes x 16B = 1KB fully contiguous (fragment layout).
__device__ __forceinline__ void ldslice(const ushort_t* slot, int g, int w, int lane,
                                        u32x4 (&ah)[4], u32x4 (&al)[4]) {
  const ushort_t* b = slot + (g << 14) + (w << 11) + lane * 8;
#pragma unroll
  for (int kt = 0; kt < 4; ++kt) {
    ah[kt] = uld16(b + kt * 512);
    al[kt] = uld16(b + PLANE + kt * 512);
  }
}

__device__ __forceinline__ f32x16 mfma3(short8 ah, short8 al, short8 bh, short8 bl, f32x16 acc) {
  acc = __builtin_amdgcn_mfma_f32_32x32x16_bf16(ah, bh, acc, 0, 0, 0);
  acc = __builtin_amdgcn_mfma_f32_32x32x16_bf16(ah, bl, acc, 0, 0, 0);
  acc = __builtin_amdgcn_mfma_f32_32x32x16_bf16(al, bh, acc, 0, 0, 0);
  return acc;
}

// accumulate wave's K=64 slice against one weight matrix (round-6 layout)
__device__ __forceinline__ void mm4(f32x16& acc, const u32x4 (&ah)[4], const u32x4 (&al)[4],
                                    const ushort_t* wh, const ushort_t* wl,
                                    int boff, int w, int bk8) {
#pragma unroll
  for (int kt = 0; kt < 4; ++kt) {
    const int ko = boff + w * 64 + kt * 16 + bk8;
    short8 bhf = *(const short8*)(wh + ko);
    short8 blf = *(const short8*)(wl + ko);
    acc = mfma3(as_s8(ah[kt]), as_s8(al[kt]), bhf, blf, acc);
  }
}

// pp join: round-6 verified 32x32 C/D layout
__device__ __forceinline__ void wr_pp1(float* pp, const f32x16& a, int w, int lane) {
  int col = lane & 31, h5 = lane >> 5;
  float* base = pp + w * 1056 + col;
#pragma unroll
  for (int r = 0; r < 16; ++r) {
    int row = (r & 3) + 8 * (r >> 2) + 4 * h5;
    base[row * 33] = a[r];
  }
}
__device__ __forceinline__ void rd_pp1(const float* pp, int row, int cp,
                                       float& c, float& h) {
  float cs = 0.f, hs = 0.f;
#pragma unroll
  for (int w = 0; w < 8; ++w) {
    cs += pp[w * 1056 + row * 33 + cp];
    hs += pp[w * 1056 + row * 33 + cp + 16];
  }
  c = cs; h = hs;
}

// ---------------- main persistent cooperative kernel -----------------------
extern "C" __global__ void __launch_bounds__(512, 1)
rnn_main(const float* __restrict__ x, float* __restrict__ out, char* __restrict__ ws) {
  __shared__ float pp0[8 * 1056];         // 33.8 KB partials (matrix 0)
  __shared__ float pp1[8 * 1056];         // 33.8 KB partials (matrix 1)

  ushort_t* stg = (ushort_t*)(ws + WS_ST);
  unsigned* flags = (unsigned*)(ws + WS_BAR);
  const ushort_t* w0h = (const ushort_t*)(ws + WS_W0T_HI);
  const ushort_t* w0l = (const ushort_t*)(ws + WS_W0T_LO);
  const ushort_t* wsh = (const ushort_t*)(ws + WS_WST_HI);
  const ushort_t* wsl = (const ushort_t*)(ws + WS_WST_LO);

  const int tid = threadIdx.x;
  const int wg = blockIdx.x;
  const int g = wg >> 5, pt = wg & 31;    // 8 row-groups x 32 col-WGs; XCD = pt%8
  const int r0 = g * 32;
  const int w = tid >> 6, lane = tid & 63;
  const int lr = lane & 31;
  const int bk8 = (lane >> 5) * 8;
  const int jc = pt * 16 + (lr & 15) + (lr >> 4) * 512;  // weight col for B-frags
  const int b512 = jc * 512, b1024 = jc * 1024;
  const int q0 = 4 * w;                   // wave's 4 producers (K-slice owners)

  const int erow = tid >> 4, ecp = tid & 15;      // thread's owned output element
  const int orow = r0 + erow, ocol = pt * 16 + ecp;
  const int oeo = orow * 512 + ocol;              // linear (for out)
  const int fo = faddr(orow, ocol);               // fragment offset (for state)

  // register-resident gate-input chain
  float h_reg = bf2f(stg[fo]) + bf2f(stg[PLANE + fo]);
  float s0_r, s1_r, s2_r, s3_r, s5_r, sum;

  u32x4 ah[4], al[4], a3h[4], a3l[4];

  for (int t = 0; t < 400; ++t) {
    const unsigned base = 5u * (unsigned)t;

    // ===== stage A: s0 = h + sig(c)*(tanh(hh) - h), A=[x|h], W0 ============
    {
      f32x16 acc = {};
      // x-part (K 0..511): no flag dependency — runs while producers finish
      const float* xr = x + (size_t)t * 131072 + (size_t)(r0 + lr) * 512;
#pragma unroll
      for (int kt = 0; kt < 4; ++kt) {
        const int k = w * 64 + kt * 16 + bk8;
        short8 xh, xl; xcvt(xr + k, xh, xl);
        short8 bhf = *(const short8*)(w0h + b1024 + k);
        short8 blf = *(const short8*)(w0l + b1024 + k);
        acc = mfma3(xh, xl, bhf, blf, acc);
      }
      pollw(flags, g, q0, base, lane);    // E flags of t-1 (h producers)
      ldslice(stg + 0 * SLOT_ELEMS, g, w, lane, ah, al);
      mm4(acc, ah, al, w0h, w0l, b1024 + 512, w, bk8);
      wr_pp1(pp0, acc, w, lane);
      __syncthreads();
      float c, hh; rd_pp1(pp0, erow, ecp, c, hh);
      s0_r = h_reg + sigf(c) * (tanhf(hh) - h_reg);
      st_state(stg + 1 * SLOT_ELEMS, fo, s0_r, tid);
    }
    set_flag(flags, g, pt, base + 1);

    // ===== stage B: s1 = f(s0, tanh, Ws[0]) ================================
    {
      pollw(flags, g, q0, base + 1, lane);
      ldslice(stg + 1 * SLOT_ELEMS, g, w, lane, ah, al);
      f32x16 acc = {};
      mm4(acc, ah, al, wsh + 0 * 524288, wsl + 0 * 524288, b512, w, bk8);
      wr_pp1(pp0, acc, w, lane);
      __syncthreads();
      float c, hh; rd_pp1(pp0, erow, ecp, c, hh);
      s1_r = s0_r + sigf(c) * (tanhf(hh) - s0_r);
      sum = s1_r;
      st_state(stg + 2 * SLOT_ELEMS, fo, s1_r, tid);
    }
    set_flag(flags, g, pt, base + 2);

    // ===== stage C: s2(relu,Ws1) s3(relu,Ws2) s4(ident,Ws3) from s1 ========
    {
      pollw(flags, g, q0, base + 2, lane);
      ldslice(stg + 2 * SLOT_ELEMS, g, w, lane, ah, al);
      f32x16 acc2 = {}, acc3 = {}, acc4 = {};
      mm4(acc2, ah, al, wsh + 1 * 524288, wsl + 1 * 524288, b512, w, bk8);
      mm4(acc3, ah, al, wsh + 2 * 524288, wsl + 2 * 524288, b512, w, bk8);
      mm4(acc4, ah, al, wsh + 3 * 524288, wsl + 3 * 524288, b512, w, bk8);
      wr_pp1(pp0, acc2, w, lane);
      wr_pp1(pp1, acc3, w, lane);
      __syncthreads();
      float c, hh;
      rd_pp1(pp0, erow, ecp, c, hh);
      s2_r = s1_r + sigf(c) * (fmaxf(hh, 0.f) - s1_r);
      sum += s2_r;
      st_state(stg + 3 * SLOT_ELEMS, fo, s2_r, tid);
      rd_pp1(pp1, erow, ecp, c, hh);
      s3_r = s1_r + sigf(c) * (fmaxf(hh, 0.f) - s1_r);
      sum += s3_r;
      st_state(stg + 4 * SLOT_ELEMS, fo, s3_r, tid);
      set_flag(flags, g, pt, base + 3);   // D needs only s2/s3 (barrier inside)
      wr_pp1(pp0, acc4, w, lane);         // s4: concat-only
      __syncthreads();
      rd_pp1(pp0, erow, ecp, c, hh);
      sum += s1_r + sigf(c) * (hh - s1_r);
    }

    // ===== stage D: s5 = f(s2,tanh,Ws4); s7 = f(s3,tanh,Ws6) ===============
    {
      pollw(flags, g, q0, base + 3, lane);
      ldslice(stg + 3 * SLOT_ELEMS, g, w, lane, ah, al);      // s2
      ldslice(stg + 4 * SLOT_ELEMS, g, w, lane, a3h, a3l);    // s3
      f32x16 acc5 = {}, acc7 = {};
      mm4(acc5, ah, al, wsh + 4 * 524288, wsl + 4 * 524288, b512, w, bk8);
      mm4(acc7, a3h, a3l, wsh + 6 * 524288, wsl + 6 * 524288, b512, w, bk8);
      __syncthreads();                    // guard pp reuse after C's s4 read
      wr_pp1(pp0, acc5, w, lane);
      wr_pp1(pp1, acc7, w, lane);
      __syncthreads();
      float c, hh;
      rd_pp1(pp0, erow, ecp, c, hh);
      s5_r = s2_r + sigf(c) * (tanhf(hh) - s2_r);
      sum += s5_r;
      st_state(stg + 5 * SLOT_ELEMS, fo, s5_r, tid);
      rd_pp1(pp1, erow, ecp, c, hh);      // s7: concat-only
      sum += s3_r + sigf(c) * (tanhf(hh) - s3_r);
    }
    set_flag(flags, g, pt, base + 4);

    // ===== stage E: s6(sigmoid,Ws5) s8(relu,Ws7) from s5; mean; h ==========
    {
      pollw(flags, g, q0, base + 4, lane);
      ldslice(stg + 5 * SLOT_ELEMS, g, w, lane, ah, al);
      f32x16 acc6 = {}, acc8 = {};
      mm4(acc6, ah, al, wsh + 5 * 524288, wsl + 5 * 524288, b512, w, bk8);
      mm4(acc8, ah, al, wsh + 7 * 524288, wsl + 7 * 524288, b512, w, bk8);
      wr_pp1(pp0, acc6, w, lane);         // guarded by set_flag(base+4) barrier
      wr_pp1(pp1, acc8, w, lane);
      __syncthreads();
      float c, hh;
      rd_pp1(pp0, erow, ecp, c, hh);
      sum += s5_r + sigf(c) * (sigf(hh) - s5_r);
      rd_pp1(pp1, erow, ecp, c, hh);
      sum += s5_r + sigf(c) * (fmaxf(hh, 0.f) - s5_r);
      h_reg = sum * 0.125f;
      __builtin_nontemporal_store(h_reg, &out[(size_t)t * 131072 + oeo]);
      if (t == 399)
        __builtin_nontemporal_store(h_reg, &out[(size_t)400 * 131072 + oeo]);
      st_state(stg + 0 * SLOT_ELEMS, fo, h_reg, tid);
    }
    set_flag(flags, g, pt, base + 5);
  }
}

// ---------------- host launch ----------------------------------------------
extern "C" void kernel_launch(void* const* d_in, const int* in_sizes, int n_in,
                              void* d_out, int out_size, void* d_ws, size_t ws_size,
                              hipStream_t stream) {
  const float* x  = (const float*)d_in[0];
  const float* h0 = (const float*)d_in[1];
  const float* W0 = (const float*)d_in[2];
  const float* Ws = (const float*)d_in[3];
  float* out = (float*)d_out;
  char* ws = (char*)d_ws;

  (void)in_sizes; (void)n_in; (void)out_size; (void)ws_size;

  (void)hipMemsetAsync(ws + WS_BAR, 0, 16384, stream);
  hipLaunchKernelGGL(prep_kernel, dim3(2048), dim3(256), 0, stream, W0, Ws, h0, ws);

  void* args[3] = {(void*)&x, (void*)&out, (void*)&ws};
  (void)hipLaunchCooperativeKernel((void*)rnn_main, dim3(256), dim3(512), args, 0, stream);
}